// Round 13
// baseline (14576.891 us; speedup 1.0000x reference)
//
#include <hip/hip_runtime.h>
#include <cmath>

#define LEAK 0.95f
#define ILEAK 0.05f

typedef float f4 __attribute__((ext_vector_type(4)));
typedef unsigned long long ull;

// ---------------- Phase 1: u = x @ W_in^T (fp32 tiled GEMM) ----------------
__global__ __launch_bounds__(256) void resv_gemm_uin(
    const float* __restrict__ A, const float* __restrict__ Bm,
    float* __restrict__ C, int M, int N, int K)
{
    __shared__ float As[16][68];
    __shared__ float Bs[16][68];
    const int tid = threadIdx.x;
    const int m0 = blockIdx.y * 64;
    const int n0 = blockIdx.x * 64;
    const int lm = tid >> 2;
    const int lk = (tid & 3) * 4;
    const int ty = tid >> 4;
    const int tx = tid & 15;

    float acc[4][4];
#pragma unroll
    for (int i = 0; i < 4; ++i)
#pragma unroll
        for (int j = 0; j < 4; ++j) acc[i][j] = 0.f;

    const float* Aptr = A + (size_t)(m0 + lm) * K + lk;
    const float* Bptr = Bm + (size_t)(n0 + lm) * K + lk;

    for (int k0 = 0; k0 < K; k0 += 16) {
        float4 av = *(const float4*)(Aptr + k0);
        float4 bv = *(const float4*)(Bptr + k0);
        __syncthreads();
        As[lk + 0][lm] = av.x; As[lk + 1][lm] = av.y;
        As[lk + 2][lm] = av.z; As[lk + 3][lm] = av.w;
        Bs[lk + 0][lm] = bv.x; Bs[lk + 1][lm] = bv.y;
        Bs[lk + 2][lm] = bv.z; Bs[lk + 3][lm] = bv.w;
        __syncthreads();
#pragma unroll
        for (int kk = 0; kk < 16; ++kk) {
            float4 a = *(const float4*)(&As[kk][ty * 4]);
            float4 b = *(const float4*)(&Bs[kk][tx * 4]);
            acc[0][0] += a.x * b.x; acc[0][1] += a.x * b.y; acc[0][2] += a.x * b.z; acc[0][3] += a.x * b.w;
            acc[1][0] += a.y * b.x; acc[1][1] += a.y * b.y; acc[1][2] += a.y * b.z; acc[1][3] += a.y * b.w;
            acc[2][0] += a.z * b.x; acc[2][1] += a.z * b.y; acc[2][2] += a.z * b.z; acc[2][3] += a.z * b.w;
            acc[3][0] += a.w * b.x; acc[3][1] += a.w * b.y; acc[3][2] += a.w * b.z; acc[3][3] += a.w * b.w;
        }
    }
    float* Cp = C + (size_t)(m0 + ty * 4) * N + n0 + tx * 4;
#pragma unroll
    for (int i = 0; i < 4; ++i) {
        float4 v = make_float4(acc[i][0], acc[i][1], acc[i][2], acc[i][3]);
        *(float4*)(Cp + (size_t)i * N) = v;
    }
}

// ---------------- Phase 2: reservoir recurrence, data-tagged sync ---------
// r12 sync skeleton (sentinel tag-poll, 3 barriers) + the r10 compute
// mapping with both of its killers fixed:
//  - pairs layout [slot][g][h][b] (b innermost): staging -> LDS [h][b] is a
//    LINEAR copy; finish publish writes pair idx h0*4+tid = 128 consecutive
//    ull = 8 full 128B lines (r11-proven full-line write-through).
//  - compute: lane = (row-group gI, k-lane li), k = w*256+li+8j interleave.
//    One ds_read_b128 = 1 k x 4 batches, 8 uniq addrs spanning all 32 banks,
//    16 FMA/read, 32 reads/lane -> 128 LDS instr/CU/step (4x fewer than r12,
//    whose 512 x ~12cy ~= 2.5us/step was ~half the step time).
//  - VGPR discipline (r10/r11 died at VGPR=256 spill, VALUBusy 13%): poll
//    stores each pair's low32 to LDS immediately (no v[16] array).
__global__ __launch_bounds__(256, 1) void resv_recur(
    const float* __restrict__ Wres,   // [1024][1024]
    float* __restrict__ out,          // [32][2048][1024] (pre-filled with u)
    ull* __restrict__ pairs)          // ws: [2 slots][8 g][1024 h][4 b] pairs
{
    constexpr int H = 1024, S = 2048;
    extern __shared__ float sm[];
    float* prevI = sm;                 // [1024 h][4 b] floats (16 KB)
    float* uL    = sm + 4096;          // [2][2048] double-buffered u (16 KB)
    float* red   = sm + 8192;          // [4 q][32 row][4 b] floats (2 KB)

    const int tid = threadIdx.x;
    const int g  = blockIdx.x & 7;
    const int r  = blockIdx.x >> 3;
    const int h0 = r * 32;
    const int b0 = g * 4;

    const int w  = tid >> 6;           // wave = k-quarter
    const int l  = tid & 63;
    const int gI = l >> 3;             // row-group 0..7 (rows 4gI..4gI+3)
    const int li = l & 7;              // k-lane within group

    // ---- one-time: W[h0+4gI+rr][w*256+li+8j] into 128 scalar registers ----
    float Wreg[128];
#pragma unroll
    for (int rr = 0; rr < 4; ++rr) {
        const float* wr = Wres + (size_t)(h0 + 4 * gI + rr) * H + (w * 256 + li);
#pragma unroll
        for (int j = 0; j < 32; ++j) Wreg[rr * 32 + j] = wr[8 * j];
    }

    const int fb  = tid & 3;           // finish: batch
    const int frw = tid >> 2;          // finish: row (tid<128 -> frw<32)
    float pv = 0.f;                    // finish thread's own previous value

    for (int t = 0; t < S; ++t) {
        // ---- stage u[t..t+15] into double buffer (own region, plain) ----
        if ((t & 15) == 0) {
            float* uB = uL + ((t >> 4) & 1) * 2048;
            for (int c = tid; c < 512; c += 256) {
                int rw4 = c & 7, b = (c >> 3) & 3, tt = c >> 5;
                const float4* src =
                    (const float4*)(out + ((size_t)(b0 + b) * S + (t + tt)) * H + h0);
                ((float4*)uB)[(tt * 4 + b) * 8 + rw4] = src[rw4];
            }
        }
        // ---- poll: sentinel wait (4/lane), then bulk-to-LDS + verify ----
        {
            const ull* src = pairs + ((size_t)((t & 1) * 8 + g)) * 4096;
            const unsigned tgt = (unsigned)t;
            // 1) sentinel wait: c = 0,5,10,15
            for (;;) {
                ull s0 = __hip_atomic_load(src + 0 * 256 + tid, __ATOMIC_RELAXED,
                                           __HIP_MEMORY_SCOPE_AGENT);
                ull s1 = __hip_atomic_load(src + 5 * 256 + tid, __ATOMIC_RELAXED,
                                           __HIP_MEMORY_SCOPE_AGENT);
                ull s2 = __hip_atomic_load(src + 10 * 256 + tid, __ATOMIC_RELAXED,
                                           __HIP_MEMORY_SCOPE_AGENT);
                ull s3 = __hip_atomic_load(src + 15 * 256 + tid, __ATOMIC_RELAXED,
                                           __HIP_MEMORY_SCOPE_AGENT);
                int ok = ((unsigned)(s0 >> 32) == tgt) & ((unsigned)(s1 >> 32) == tgt)
                       & ((unsigned)(s2 >> 32) == tgt) & ((unsigned)(s3 >> 32) == tgt);
                if (__all(ok)) {
                    prevI[0 * 256 + tid]  = __uint_as_float((unsigned)s0);
                    prevI[5 * 256 + tid]  = __uint_as_float((unsigned)s1);
                    prevI[10 * 256 + tid] = __uint_as_float((unsigned)s2);
                    prevI[15 * 256 + tid] = __uint_as_float((unsigned)s3);
                    break;
                }
            }
            // 2) bulk-load remaining 12 straight to LDS, verify, rare retry
            for (;;) {
                int ok = 1;
#pragma unroll
                for (int c = 0; c < 16; ++c) {
                    if (c == 0 || c == 5 || c == 10 || c == 15) continue;
                    ull v = __hip_atomic_load(src + c * 256 + tid, __ATOMIC_RELAXED,
                                              __HIP_MEMORY_SCOPE_AGENT);
                    ok &= ((unsigned)(v >> 32) == tgt);
                    prevI[c * 256 + tid] = __uint_as_float((unsigned)v);
                }
                if (__all(ok)) break;
            }
        }
        __syncthreads();

        // ---- compute: 4 rows x 4 batches/lane; 32 b128 reads, 16 FMA each --
        f4 a0 = (f4)(0.f), a1 = (f4)(0.f), a2 = (f4)(0.f), a3 = (f4)(0.f);
        const f4* P = (const f4*)prevI;    // P[h] = prev[h][b0..b0+3]
        const int kB = w * 256 + li;
#pragma unroll
        for (int j = 0; j < 32; ++j) {
            f4 pk = P[kB + 8 * j];         // 8 uniq addrs/instr, all 32 banks
            a0 += Wreg[j]      * pk;
            a1 += Wreg[32 + j] * pk;
            a2 += Wreg[64 + j] * pk;
            a3 += Wreg[96 + j] * pk;
        }
        // reduce over the 8 k-lanes of the group (xor 1,2,4)
#define RED8(A) \
        A.x += __shfl_xor(A.x, m, 64); A.y += __shfl_xor(A.y, m, 64); \
        A.z += __shfl_xor(A.z, m, 64); A.w += __shfl_xor(A.w, m, 64);
#pragma unroll
        for (int m = 1; m <= 4; m <<= 1) { RED8(a0) RED8(a1) RED8(a2) RED8(a3) }
#undef RED8
        if (li == 0) {
            f4* rd = (f4*)red + (w * 32 + 4 * gI);
            rd[0] = a0; rd[1] = a1; rd[2] = a2; rd[3] = a3;
        }
        __syncthreads();

        // ---- finish (tid<128): publish tagged pair, FULL-LINE order ----
        if (tid < 128) {
            float sum = red[(0 * 32 + frw) * 4 + fb] + red[(1 * 32 + frw) * 4 + fb]
                      + red[(2 * 32 + frw) * 4 + fb] + red[(3 * 32 + frw) * 4 + fb];
            float uv = uL[((t >> 4) & 1) * 2048 + (((t & 15) * 4 + fb) << 5) + frw];
            float ns = LEAK * tanhf(uv + sum) + ILEAK * pv;
            pv = ns;
            ull pk = ((ull)(unsigned)(t + 1) << 32) | (ull)__float_as_uint(ns);
            // pair idx (h0+frw)*4+fb == h0*4+tid: 128 consecutive ull
            __hip_atomic_store(
                pairs + ((size_t)(((t + 1) & 1) * 8 + g)) * 4096 + h0 * 4 + tid,
                pk, __ATOMIC_RELAXED, __HIP_MEMORY_SCOPE_AGENT);
            out[((size_t)(b0 + fb) * S + t) * H + h0 + frw] = ns;
        }
        __syncthreads();
    }
}

extern "C" void kernel_launch(void* const* d_in, const int* in_sizes, int n_in,
                              void* d_out, int out_size, void* d_ws, size_t ws_size,
                              hipStream_t stream)
{
    const float* x    = (const float*)d_in[0];   // [32][2048][512]
    const float* Win  = (const float*)d_in[1];   // [1024][512]
    const float* Wres = (const float*)d_in[2];   // [1024][1024]
    float* out = (float*)d_out;                  // [32][2048][1024]

    ull* pairs = (ull*)d_ws;                     // 2*8*4096*8 = 524288 B

    // zero pairs every launch: (tag 0, 0.0f) == step-0 initial state
    hipMemsetAsync(d_ws, 0, 524288, stream);

    // phase 1: u = x @ W_in^T into d_out
    dim3 gemm_grid(1024 / 64, 65536 / 64);
    resv_gemm_uin<<<gemm_grid, 256, 0, stream>>>(x, Win, out, 65536, 1024, 512);

    // phase 2: recurrence. 96KB dynamic LDS pins exactly 1 wg/CU
    // (co-residency of all 256 wgs proven rounds 1-12).
    constexpr int kLds = 96 * 1024;
    hipFuncSetAttribute((const void*)resv_recur,
                        hipFuncAttributeMaxDynamicSharedMemorySize, kLds);
    resv_recur<<<dim3(256), dim3(256), kLds, stream>>>(Wres, out, pairs);
}